// Round 9
// baseline (314.186 us; speedup 1.0000x reference)
//
#include <hip/hip_runtime.h>
#include <hip/hip_bf16.h>
#include <math.h>

#define B_  32
#define L_  4096
#define H_  512
#define V_  32000
#define MBLK 64

typedef __attribute__((ext_vector_type(4))) float f32x4;
typedef __attribute__((ext_vector_type(2))) float f32x2;
typedef __attribute__((ext_vector_type(8))) short short8;
typedef __attribute__((ext_vector_type(4))) unsigned short u16x4;

// global_load_lds: per-lane global src, wave-uniform LDS base + lane*16 dest
#define GLL16(gp, lp) __builtin_amdgcn_global_load_lds( \
    (const __attribute__((address_space(1))) void*)(gp), \
    (__attribute__((address_space(3))) void*)(lp), 16, 0, 0)

__device__ __forceinline__ unsigned short bf16_rne(float x){
  union { float f; unsigned int u; } v; v.f = x;
  unsigned int u = v.u;
  return (unsigned short)((u + 0x7FFFu + ((u >> 16) & 1u)) >> 16);
}
// cheap tanh: exact saturation, ~1e-6 abs err
__device__ __forceinline__ float tanh_cheap(float x){
  float e = __expf(x + x);
  return 1.0f - 2.0f * __builtin_amdgcn_rcpf(e + 1.0f);
}
// packed f32x8 -> bf16x8 via v_cvt_pk_bf16_f32
__device__ __forceinline__ short8 cvt8(f32x4 a, f32x4 b){
  union { __hip_bfloat162 h[4]; short8 s; } u;
  u.h[0] = __float22bfloat162_rn(make_float2(a[0], a[1]));
  u.h[1] = __float22bfloat162_rn(make_float2(a[2], a[3]));
  u.h[2] = __float22bfloat162_rn(make_float2(b[0], b[1]));
  u.h[3] = __float22bfloat162_rn(make_float2(b[2], b[3]));
  return u.s;
}

// ---------------- W2 -> bf16 (512 KB, per call) ----------------
__global__ __launch_bounds__(256) void k_convert_w2(
    const float* __restrict__ w2, unsigned short* __restrict__ hi){
  int i = (blockIdx.x * 256 + threadIdx.x) * 4;
  f32x4 v = *(const f32x4*)(w2 + i);
  u16x4 h;
  #pragma unroll
  for (int e = 0; e < 4; ++e) h[e] = bf16_rne(v[e]);
  *(u16x4*)(hi + i) = h;
}

// ---------------- gates ----------------
__global__ __launch_bounds__(256) void k_gates(
    const float* __restrict__ x, const float* __restrict__ h0,
    const float* __restrict__ Wih, const float* __restrict__ Whh,
    const float* __restrict__ bih, const float* __restrict__ bhh,
    float* __restrict__ gates){
  __shared__ float sx[H_], sh[H_];
  int b = blockIdx.y, t = threadIdx.x;
  sx[t] = x[b*H_ + t]; sx[t+256] = x[b*H_ + t + 256];
  sh[t] = h0[b*H_ + t]; sh[t+256] = h0[b*H_ + t + 256];
  __syncthreads();
  int j = blockIdx.x * 256 + t;
  const float* wi = Wih + j*H_;
  const float* wh = Whh + j*H_;
  float acc = bih[j] + bhh[j];
  #pragma unroll 4
  for (int k = 0; k < H_; k += 4) {
    f32x4 a = *(const f32x4*)(wi + k);
    f32x4 c = *(const f32x4*)(wh + k);
    acc += a[0]*sx[k] + a[1]*sx[k+1] + a[2]*sx[k+2] + a[3]*sx[k+3];
    acc += c[0]*sh[k] + c[1]*sh[k+1] + c[2]*sh[k+2] + c[3]*sh[k+3];
  }
  gates[b*2048 + j] = acc;
}

// ---------------- LSTM cell (exact tanh; mirrors h into f32 cc + bf16 ccb) -
__global__ __launch_bounds__(256) void k_lstm(
    const float* __restrict__ gates, const float* __restrict__ c0,
    float* __restrict__ out_h, float* __restrict__ out_c, float* __restrict__ cc,
    unsigned short* __restrict__ ccb){
  int idx = blockIdx.x * 256 + threadIdx.x;   // 16384
  int b = idx >> 9, hh = idx & 511;
  const float* g = gates + b*2048;
  float gi = g[hh], gf = g[512+hh], gg = g[1024+hh], go = g[1536+hh];
  float si = 1.f/(1.f+expf(-gi));
  float sf = 1.f/(1.f+expf(-gf));
  float so = 1.f/(1.f+expf(-go));
  float c = sf * c0[idx] + si * tanhf(gg);
  float h = so * tanhf(c);
  out_h[idx] = h; out_c[idx] = c;
  cc[b*1024 + hh] = h;
  ccb[b*1024 + hh] = bf16_rne(h);
}

// ---------------- q = h@W1^T + b1 ----------------
__global__ __launch_bounds__(256) void k_q(
    const float* __restrict__ cc, const float* __restrict__ W1,
    const float* __restrict__ b1, float* __restrict__ q){
  __shared__ float shh[H_];
  int b = blockIdx.y, t = threadIdx.x;
  shh[t] = cc[b*1024 + t]; shh[t+256] = cc[b*1024 + t + 256];
  __syncthreads();
  int j = blockIdx.x*256 + t;
  const float* w = W1 + j*H_;
  float acc = b1[j];
  #pragma unroll 4
  for (int k = 0; k < H_; k += 4){
    f32x4 a = *(const f32x4*)(w + k);
    acc += a[0]*shh[k] + a[1]*shh[k+1] + a[2]*shh[k+2] + a[3]*shh[k+3];
  }
  q[b*H_ + j] = acc;
}

// ---------------- scores: 64-row tile, full N=512, global_load_lds staging -
// 8 waves, (512,4) -> 2 blocks/CU. Wave owns 64m x 64j (acc 64 AGPR).
// A staged as f32 via global_load_lds (2 instr/wave/step, linear LDS dest);
// bank-swizzle baked into the per-lane GLOBAL source address:
//   LDS[row][c'] = doc chunk (c'&8)|((c'&7)^(row&7)), 16B chunks, c' 0..15.
// Reader ds_read_b128 at c'=swz(g), cvt8 -> bf16 fragment (consume-side cvt).
// Per-16-lane phase: 8 bank-groups x2 = 2-way = free.
__global__ __launch_bounds__(512, 4) void k_scores(
    const float* __restrict__ doc, const unsigned short* __restrict__ w2hi,
    const float* __restrict__ qv,
    const float* __restrict__ w2b, const float* __restrict__ u1,
    const int* __restrict__ mask, float* __restrict__ scores){
  __shared__ float Af[2][MBLK][16][4];       // 32 KB (2 x 16 KB)
  __shared__ float2 s_qu[512];               // 4 KB
  __shared__ float s_part[8][MBLK];          // 2 KB
  int t = threadIdx.x;
  int row0 = blockIdx.x * MBLK;
  int b = row0 >> 12;
  s_qu[t] = make_float2(qv[b*512 + t] + w2b[t], u1[t]);

  int wave = t >> 6, lane = t & 63;
  int lrow = lane & 15, lk = lane >> 4;

  // gll per-lane source (swizzled), dest linear
  int r4 = lane >> 4;                 // 0..3
  int cpr = lane & 15;                // LDS chunk c'
  int rA = wave*8 + r4, rB = rA + 4;  // rows this lane feeds
  int csA = (cpr & 8) | ((cpr & 7) ^ (rA & 7));
  int csB = (cpr & 8) | ((cpr & 7) ^ (rB & 7));
  const float* gA = doc + (((long)(row0 + rA)) << 9) + csA*4;
  const float* gB = doc + (((long)(row0 + rB)) << 9) + csB*4;

  int j0 = wave * 64;
  const unsigned short* pbh = w2hi + (j0 + lrow)*512 + lk*8;

  f32x4 acc[4][4];  // [mt][jj]
  #pragma unroll
  for (int mt = 0; mt < 4; ++mt)
    #pragma unroll
    for (int jj = 0; jj < 4; ++jj)
      acc[mt][jj] = (f32x4){0.f, 0.f, 0.f, 0.f};

  // prologue: stage step 0
  GLL16(gA, &Af[0][wave*8][0][0]);
  GLL16(gB, &Af[0][wave*8 + 4][0][0]);
  __syncthreads();

  int buf = 0;
  for (int s = 0; s < 8; ++s){
    if (s < 7){   // prefetch next K-step into other buffer (off critical path)
      GLL16(gA + (s+1)*64, &Af[buf^1][wave*8][0][0]);
      GLL16(gB + (s+1)*64, &Af[buf^1][wave*8 + 4][0][0]);
    }
    #pragma unroll
    for (int ktl = 0; ktl < 2; ++ktl){
      short8 bh[4];
      int ko = s*64 + ktl*32;
      #pragma unroll
      for (int jj = 0; jj < 4; ++jj)
        bh[jj] = *(const short8*)(pbh + jj*8192 + ko);
      short8 a[4];
      #pragma unroll
      for (int mt = 0; mt < 4; ++mt){
        int row = mt*16 + lrow;
        int g0 = ktl*8 + lk*2;                       // orig 16B-chunk (even)
        int ca = (g0 & 8) | ((g0 & 7) ^ (row & 7));  // swizzled position
        int cb = ca ^ 1;                             // chunk g0+1
        f32x4 va = *(const f32x4*)&Af[buf][row][ca][0];
        f32x4 vb = *(const f32x4*)&Af[buf][row][cb][0];
        a[mt] = cvt8(va, vb);
      }
      #pragma unroll
      for (int jj = 0; jj < 4; ++jj)
        #pragma unroll
        for (int mt = 0; mt < 4; ++mt)
          acc[mt][jj] = __builtin_amdgcn_mfma_f32_16x16x32_bf16(bh[jj], a[mt], acc[mt][jj], 0, 0, 0);
    }
    __syncthreads();   // drains gll (vmcnt) + all waves done with buf
    buf ^= 1;
  }

  // epilogue: tanh + u1-dot over wave's 64 j's, per m-row
  #pragma unroll
  for (int mt = 0; mt < 4; ++mt){
    float p = 0.f;
    #pragma unroll
    for (int jj = 0; jj < 4; ++jj){
      #pragma unroll
      for (int r = 0; r < 4; ++r){
        int j = j0 + jj*16 + lk*4 + r;
        float2 qu = s_qu[j];
        p += tanh_cheap(acc[mt][jj][r] + qu.x) * qu.y;
      }
    }
    p += __shfl_xor(p, 16);
    p += __shfl_xor(p, 32);
    if (lane < 16) s_part[wave][mt*16 + lrow] = p;
  }
  __syncthreads();
  if (t < MBLK){
    float ssum = 0.f;
    #pragma unroll
    for (int w = 0; w < 8; ++w) ssum += s_part[w][t];
    int gl = row0 + t;
    scores[gl] = mask[gl] ? ssum : -INFINITY;
  }
}

// ---------------- softmax over L per row b (in place) ----------------
__global__ __launch_bounds__(256) void k_softmax(float* __restrict__ sc){
  __shared__ float red[256];
  int b = blockIdx.x, t = threadIdx.x;
  float v[16]; float m = -INFINITY;
  #pragma unroll
  for (int i = 0; i < 16; ++i){ v[i] = sc[b*4096 + i*256 + t]; m = fmaxf(m, v[i]); }
  red[t] = m; __syncthreads();
  for (int s = 128; s > 0; s >>= 1){ if (t < s) red[t] = fmaxf(red[t], red[t+s]); __syncthreads(); }
  m = red[0]; __syncthreads();
  float sum = 0.f;
  #pragma unroll
  for (int i = 0; i < 16; ++i){ v[i] = expf(v[i] - m); sum += v[i]; }
  red[t] = sum; __syncthreads();
  for (int s = 128; s > 0; s >>= 1){ if (t < s) red[t] += red[t+s]; __syncthreads(); }
  float inv = 1.f / red[0];
  #pragma unroll
  for (int i = 0; i < 16; ++i) sc[b*4096 + i*256 + t] = v[i] * inv;
}

// ---------------- context partials ----------------
#define CCH 64
__global__ __launch_bounds__(256) void k_ctx(
    const float* __restrict__ attn, const float* __restrict__ doc,
    float* __restrict__ ctxp){
  __shared__ float sa[CCH];
  int b = blockIdx.y, ch = blockIdx.x, t = threadIdx.x;
  int l0 = ch * CCH;
  if (t < CCH) sa[t] = attn[b*4096 + l0 + t];
  __syncthreads();
  const float* dp = doc + (((long)b*4096 + l0) << 9) + t*2;
  float ax = 0.f, ay = 0.f;
  #pragma unroll 4
  for (int l = 0; l < CCH; ++l){
    f32x2 d = *(const f32x2*)dp;
    float a = sa[l];
    ax += a * d[0]; ay += a * d[1];
    dp += 512;
  }
  int o = (b*64 + ch)*512 + t*2;
  ctxp[o] = ax; ctxp[o+1] = ay;
}

__global__ __launch_bounds__(256) void k_ctx_reduce(
    const float* __restrict__ ctxp, float* __restrict__ cc,
    unsigned short* __restrict__ ccb){
  int idx = blockIdx.x*256 + threadIdx.x;  // 16384
  int b = idx >> 9, hh = idx & 511;
  float s = 0.f;
  #pragma unroll 8
  for (int ch = 0; ch < 64; ++ch) s += ctxp[(b*64 + ch)*512 + hh];
  cc[b*1024 + 512 + hh] = s;
  ccb[b*1024 + 512 + hh] = bf16_rne(s);
}

// ---------------- output = cc @ Wout^T + bout, bf16 MFMA ----------------
__global__ __launch_bounds__(256) void k_out(
    const unsigned short* __restrict__ ccb, const float* __restrict__ Wout,
    const float* __restrict__ bout, float* __restrict__ out){
  __shared__ short Ccb[32][128][8];      // 64 KB
  __shared__ float s_out[32][65];        // 8.3 KB
  int t = threadIdx.x, wave = t >> 6, lane = t & 63;
  int v0 = blockIdx.x * 64;
  #pragma unroll
  for (int i = 0; i < 16; ++i){
    int c16 = i*256 + t;               // 16B-chunk index over 4096
    int bb = c16 >> 7, ch = c16 & 127;
    int chsw = (ch & ~7) | ((ch & 7) ^ (bb & 7));
    *(short8*)&Ccb[bb][chsw][0] = *(const short8*)(ccb + c16*8);
  }
  __syncthreads();

  int lrow = lane & 15, lk = lane >> 4;
  int vrow = v0 + wave*16 + lrow;
  const float* wptr = Wout + (long)vrow*1024 + lk*8;
  f32x4 acc[2];
  acc[0] = (f32x4){0.f,0.f,0.f,0.f};
  acc[1] = (f32x4){0.f,0.f,0.f,0.f};
  int sw = lrow & 7;
  f32x4 w0 = *(const f32x4*)(wptr);
  f32x4 w1 = *(const f32x4*)(wptr + 4);
  #pragma unroll 4
  for (int ks = 0; ks < 32; ++ks){
    f32x4 nw0, nw1;
    if (ks < 31){
      nw0 = *(const f32x4*)(wptr + (ks+1)*32);
      nw1 = *(const f32x4*)(wptr + (ks+1)*32 + 4);
    }
    short8 bfrag = cvt8(w0, w1);
    int ch = ks*4 + lk;
    int chsw = (ch & ~7) | ((ch & 7) ^ sw);
    short8 a0 = *(const short8*)&Ccb[lrow][chsw][0];
    short8 a1 = *(const short8*)&Ccb[16 + lrow][chsw][0];
    acc[0] = __builtin_amdgcn_mfma_f32_16x16x32_bf16(bfrag, a0, acc[0], 0, 0, 0);
    acc[1] = __builtin_amdgcn_mfma_f32_16x16x32_bf16(bfrag, a1, acc[1], 0, 0, 0);
    w0 = nw0; w1 = nw1;
  }
  #pragma unroll
  for (int mt = 0; mt < 2; ++mt)
    #pragma unroll
    for (int r = 0; r < 4; ++r)
      s_out[mt*16 + lrow][wave*16 + lk*4 + r] = acc[mt][r];
  __syncthreads();
  int vcol = t & 63, bq = t >> 6;
  float bo = bout[v0 + vcol];
  #pragma unroll
  for (int bb = 0; bb < 8; ++bb){
    int brow = bb*4 + bq;
    out[(long)brow*V_ + v0 + vcol] = s_out[brow][vcol] + bo;
  }
}

extern "C" void kernel_launch(void* const* d_in, const int* in_sizes, int n_in,
                              void* d_out, int out_size, void* d_ws, size_t ws_size,
                              hipStream_t stream){
  const float* x    = (const float*)d_in[0];
  const float* h0   = (const float*)d_in[1];
  const float* c0   = (const float*)d_in[2];
  const float* doc  = (const float*)d_in[3];
  const int*   mask = (const int*)d_in[4];
  const float* Wih  = (const float*)d_in[5];
  const float* Whh  = (const float*)d_in[6];
  const float* bih  = (const float*)d_in[7];
  const float* bhh  = (const float*)d_in[8];
  const float* W1   = (const float*)d_in[9];
  const float* b1   = (const float*)d_in[10];
  const float* W2   = (const float*)d_in[11];
  const float* b2   = (const float*)d_in[12];
  const float* u1   = (const float*)d_in[13];
  const float* Wo   = (const float*)d_in[14];
  const float* bo   = (const float*)d_in[15];
  float* out  = (float*)d_out;
  float* outh = out + B_*V_;
  float* outc = outh + B_*H_;

  float* ws    = (float*)d_ws;
  float* gates = ws;                  // 65536 f32
  float* q     = gates + 65536;       // 16384
  float* cc    = q + 16384;           // 32768
  float* attn  = cc + 32768;          // 131072
  float* ctxp  = attn + 131072;       // 1048576
  unsigned short* w2hi = (unsigned short*)(ctxp + 1048576); // 262144 u16
  unsigned short* ccb  = w2hi + 262144;                      // 32768 u16

  hipLaunchKernelGGL(k_convert_w2, dim3(256), dim3(256), 0, stream, W2, w2hi);
  hipLaunchKernelGGL(k_gates, dim3(8, 32), dim3(256), 0, stream, x, h0, Wih, Whh, bih, bhh, gates);
  hipLaunchKernelGGL(k_lstm, dim3(64), dim3(256), 0, stream, gates, c0, outh, outc, cc, ccb);
  hipLaunchKernelGGL(k_q, dim3(2, 32), dim3(256), 0, stream, cc, W1, b1, q);
  hipLaunchKernelGGL(k_scores, dim3(2048), dim3(512), 0, stream, doc, w2hi, q, b2, u1, mask, attn);
  hipLaunchKernelGGL(k_softmax, dim3(32), dim3(256), 0, stream, attn);
  hipLaunchKernelGGL(k_ctx, dim3(64, 32), dim3(256), 0, stream, attn, doc, ctxp);
  hipLaunchKernelGGL(k_ctx_reduce, dim3(64), dim3(256), 0, stream, ctxp, cc, ccb);
  hipLaunchKernelGGL(k_out, dim3(500), dim3(256), 0, stream, ccb, Wo, bo, out);
}

// Round 10
// 279.368 us; speedup vs baseline: 1.1246x; 1.1246x over previous
//
#include <hip/hip_runtime.h>
#include <hip/hip_bf16.h>
#include <math.h>

#define B_  32
#define L_  4096
#define H_  512
#define V_  32000
#define MBLK 64

typedef __attribute__((ext_vector_type(4))) float f32x4;
typedef __attribute__((ext_vector_type(2))) float f32x2;
typedef __attribute__((ext_vector_type(8))) short short8;
typedef __attribute__((ext_vector_type(4))) unsigned short u16x4;

__device__ __forceinline__ unsigned short bf16_rne(float x){
  union { float f; unsigned int u; } v; v.f = x;
  unsigned int u = v.u;
  return (unsigned short)((u + 0x7FFFu + ((u >> 16) & 1u)) >> 16);
}
__device__ __forceinline__ float bf16_f32(unsigned short h){
  union { unsigned int u; float f; } v; v.u = ((unsigned int)h) << 16;
  return v.f;
}
// cheap tanh: exact saturation, ~1e-6 abs err
__device__ __forceinline__ float tanh_cheap(float x){
  float e = __expf(x + x);
  return 1.0f - 2.0f * __builtin_amdgcn_rcpf(e + 1.0f);
}
// packed f32x8 -> bf16x8 via v_cvt_pk_bf16_f32
__device__ __forceinline__ short8 cvt8(f32x4 a, f32x4 b){
  union { __hip_bfloat162 h[4]; short8 s; } u;
  u.h[0] = __float22bfloat162_rn(make_float2(a[0], a[1]));
  u.h[1] = __float22bfloat162_rn(make_float2(a[2], a[3]));
  u.h[2] = __float22bfloat162_rn(make_float2(b[0], b[1]));
  u.h[3] = __float22bfloat162_rn(make_float2(b[2], b[3]));
  return u.s;
}

// ---------------- W2 -> bf16 (512 KB, per call) ----------------
__global__ __launch_bounds__(256) void k_convert_w2(
    const float* __restrict__ w2, unsigned short* __restrict__ hi){
  int i = (blockIdx.x * 256 + threadIdx.x) * 4;
  f32x4 v = *(const f32x4*)(w2 + i);
  u16x4 h;
  #pragma unroll
  for (int e = 0; e < 4; ++e) h[e] = bf16_rne(v[e]);
  *(u16x4*)(hi + i) = h;
}

// ---------------- gates ----------------
__global__ __launch_bounds__(256) void k_gates(
    const float* __restrict__ x, const float* __restrict__ h0,
    const float* __restrict__ Wih, const float* __restrict__ Whh,
    const float* __restrict__ bih, const float* __restrict__ bhh,
    float* __restrict__ gates){
  __shared__ float sx[H_], sh[H_];
  int b = blockIdx.y, t = threadIdx.x;
  sx[t] = x[b*H_ + t]; sx[t+256] = x[b*H_ + t + 256];
  sh[t] = h0[b*H_ + t]; sh[t+256] = h0[b*H_ + t + 256];
  __syncthreads();
  int j = blockIdx.x * 256 + t;
  const float* wi = Wih + j*H_;
  const float* wh = Whh + j*H_;
  float acc = bih[j] + bhh[j];
  #pragma unroll 4
  for (int k = 0; k < H_; k += 4) {
    f32x4 a = *(const f32x4*)(wi + k);
    f32x4 c = *(const f32x4*)(wh + k);
    acc += a[0]*sx[k] + a[1]*sx[k+1] + a[2]*sx[k+2] + a[3]*sx[k+3];
    acc += c[0]*sh[k] + c[1]*sh[k+1] + c[2]*sh[k+2] + c[3]*sh[k+3];
  }
  gates[b*2048 + j] = acc;
}

// ---------------- LSTM cell (exact tanh; mirrors h into f32 cc + bf16 ccb) -
__global__ __launch_bounds__(256) void k_lstm(
    const float* __restrict__ gates, const float* __restrict__ c0,
    float* __restrict__ out_h, float* __restrict__ out_c, float* __restrict__ cc,
    unsigned short* __restrict__ ccb){
  int idx = blockIdx.x * 256 + threadIdx.x;   // 16384
  int b = idx >> 9, hh = idx & 511;
  const float* g = gates + b*2048;
  float gi = g[hh], gf = g[512+hh], gg = g[1024+hh], go = g[1536+hh];
  float si = 1.f/(1.f+expf(-gi));
  float sf = 1.f/(1.f+expf(-gf));
  float so = 1.f/(1.f+expf(-go));
  float c = sf * c0[idx] + si * tanhf(gg);
  float h = so * tanhf(c);
  out_h[idx] = h; out_c[idx] = c;
  cc[b*1024 + hh] = h;
  ccb[b*1024 + hh] = bf16_rne(h);
}

// ---------------- q = h@W1^T + b1 ----------------
__global__ __launch_bounds__(256) void k_q(
    const float* __restrict__ cc, const float* __restrict__ W1,
    const float* __restrict__ b1, float* __restrict__ q){
  __shared__ float shh[H_];
  int b = blockIdx.y, t = threadIdx.x;
  shh[t] = cc[b*1024 + t]; shh[t+256] = cc[b*1024 + t + 256];
  __syncthreads();
  int j = blockIdx.x*256 + t;
  const float* w = W1 + j*H_;
  float acc = b1[j];
  #pragma unroll 4
  for (int k = 0; k < H_; k += 4){
    f32x4 a = *(const f32x4*)(w + k);
    acc += a[0]*shh[k] + a[1]*shh[k+1] + a[2]*shh[k+2] + a[3]*shh[k+3];
  }
  q[b*H_ + j] = acc;
}

// ---------------- fused scores+softmax+context over a 64-row tile ----------
// 2048 blocks x 512 thr (8 waves), (512,2). Whole doc tile (64x512 bf16,
// XOR-swizzled 16B chunks) resident in 64 KB LDS -> K-loop has NO barriers.
// Wave owns 64m x 64j (acc 64 AGPR). After j-reduction: block-local softmax
// (m_blk, e_l, sum) and ctx partial ctxp[512] = sum_l e_l * doc[l][:].
// k_combine merges the 64 blocks per batch row.
__global__ __launch_bounds__(512, 2) void k_scores_ctx(
    const float* __restrict__ doc, const unsigned short* __restrict__ w2hi,
    const float* __restrict__ qv,
    const float* __restrict__ w2b, const float* __restrict__ u1,
    const int* __restrict__ mask,
    float* __restrict__ ctxp, float* __restrict__ bm, float* __restrict__ bs){
  __shared__ short Adoc[MBLK][64][8];        // 64 KB: [row][chunk'][8 bf16]
  __shared__ float2 s_qu[512];               // 4 KB
  __shared__ float s_part[8][MBLK];          // 2 KB
  __shared__ float e_arr[MBLK];              // 256 B
  __shared__ float cpart[2][512];            // 4 KB
  int t = threadIdx.x;
  int row0 = blockIdx.x * MBLK;
  int b = row0 >> 12;
  s_qu[t] = make_float2(qv[b*512 + t] + w2b[t], u1[t]);

  // ---- stage whole tile once: thread = (row sr=t>>3, 64-float span sg=t&7)
  {
    int sr = t >> 3, sg = t & 7;
    const float* src = doc + (((long)(row0 + sr)) << 9) + sg*64;
    #pragma unroll
    for (int i = 0; i < 8; ++i){
      f32x4 a = *(const f32x4*)(src + i*8);
      f32x4 c = *(const f32x4*)(src + i*8 + 4);
      int cp = sg*8 + (i ^ (sr & 7));
      *(short8*)&Adoc[sr][cp][0] = cvt8(a, c);
    }
  }
  __syncthreads();

  int wave = t >> 6, lane = t & 63;
  int lrow = lane & 15, lk = lane >> 4;
  int j0 = wave * 64;
  const unsigned short* pbh = w2hi + (j0 + lrow)*512 + lk*8;

  f32x4 acc[4][4];  // [mt][jj]
  #pragma unroll
  for (int mt = 0; mt < 4; ++mt)
    #pragma unroll
    for (int jj = 0; jj < 4; ++jj)
      acc[mt][jj] = (f32x4){0.f, 0.f, 0.f, 0.f};

  // ---- barrier-free K-loop: 8 steps x 64 MFMA/wave
  #pragma unroll 1
  for (int s = 0; s < 8; ++s){
    short8 bh[8];
    int ko = s*64;
    #pragma unroll
    for (int jj = 0; jj < 4; ++jj){
      bh[jj]   = *(const short8*)(pbh + jj*8192 + ko);
      bh[4+jj] = *(const short8*)(pbh + jj*8192 + ko + 32);
    }
    #pragma unroll
    for (int ktl = 0; ktl < 2; ++ktl){
      short8 a[4];
      #pragma unroll
      for (int mt = 0; mt < 4; ++mt){
        int row = mt*16 + lrow;
        int g = ktl*4 + lk;                       // chunk within step (0..7)
        int cp = s*8 + (g ^ (row & 7));
        a[mt] = *(const short8*)&Adoc[row][cp][0];
      }
      #pragma unroll
      for (int jj = 0; jj < 4; ++jj)
        #pragma unroll
        for (int mt = 0; mt < 4; ++mt)
          acc[mt][jj] = __builtin_amdgcn_mfma_f32_16x16x32_bf16(bh[ktl*4 + jj], a[mt], acc[mt][jj], 0, 0, 0);
    }
  }

  // ---- epilogue: tanh + u1-dot over wave's 64 j's, per m-row
  #pragma unroll
  for (int mt = 0; mt < 4; ++mt){
    float p = 0.f;
    #pragma unroll
    for (int jj = 0; jj < 4; ++jj){
      #pragma unroll
      for (int r = 0; r < 4; ++r){
        int j = j0 + jj*16 + lk*4 + r;
        float2 qu = s_qu[j];
        p += tanh_cheap(acc[mt][jj][r] + qu.x) * qu.y;
      }
    }
    p += __shfl_xor(p, 16);
    p += __shfl_xor(p, 32);
    if (lane < 16) s_part[wave][mt*16 + lrow] = p;
  }
  __syncthreads();

  // ---- block-local softmax (rows of this tile), wave 0 only
  if (t < MBLK){
    float sl = 0.f;
    #pragma unroll
    for (int w = 0; w < 8; ++w) sl += s_part[w][t];
    int gl = row0 + t;
    bool ok = mask[gl] != 0;
    sl = ok ? sl : -INFINITY;
    float m = sl;
    #pragma unroll
    for (int o = 1; o < 64; o <<= 1) m = fmaxf(m, __shfl_xor(m, o));
    float e = ok ? __expf(sl - m) : 0.f;
    float es = e;
    #pragma unroll
    for (int o = 1; o < 64; o <<= 1) es += __shfl_xor(es, o);
    e_arr[t] = e;
    if (t == 0){ bm[blockIdx.x] = m; bs[blockIdx.x] = es; }
  }
  __syncthreads();

  // ---- ctx partial: ctxp[h] = sum_l e_l * doc[l][h], from resident tile
  {
    int p = t & 255, half = t >> 8;       // col pair 2p,2p+1; rows half*32..+32
    int c = p >> 2;                       // base chunk
    int boff = (p & 3) * 4;               // byte offset within chunk
    float a0 = 0.f, a1 = 0.f;
    int l0 = half * 32;
    #pragma unroll 8
    for (int l = l0; l < l0 + 32; ++l){
      int cp = (c & ~7) | ((c & 7) ^ (l & 7));
      unsigned v = *(const unsigned*)((const char*)&Adoc[l][cp][0] + boff);
      float e = e_arr[l];
      a0 += e * bf16_f32((unsigned short)(v & 0xffff));
      a1 += e * bf16_f32((unsigned short)(v >> 16));
    }
    cpart[half][2*p]   = a0;
    cpart[half][2*p+1] = a1;
  }
  __syncthreads();
  ctxp[(long)blockIdx.x * 512 + t] = cpart[0][t] + cpart[1][t];
}

// ---------------- combine: merge 64 block-partials per batch row ----------
__global__ __launch_bounds__(512) void k_combine(
    const float* __restrict__ ctxp, const float* __restrict__ bm,
    const float* __restrict__ bs, unsigned short* __restrict__ ccb){
  __shared__ float sw[64];
  __shared__ float sT;
  int b = blockIdx.x, t = threadIdx.x;
  if (t < 64){
    float m = bm[b*64 + t], s = bs[b*64 + t];
    float M = m;
    #pragma unroll
    for (int o = 1; o < 64; o <<= 1) M = fmaxf(M, __shfl_xor(M, o));
    float w = (m == -INFINITY) ? 0.f : __expf(m - M);
    float ts = s * w;
    #pragma unroll
    for (int o = 1; o < 64; o <<= 1) ts += __shfl_xor(ts, o);
    sw[t] = w;
    if (t == 0) sT = ts;
  }
  __syncthreads();
  float invT = 1.f / sT;
  const float* cp = ctxp + (long)b*64*512 + t;
  float acc = 0.f;
  #pragma unroll 8
  for (int blk = 0; blk < 64; ++blk) acc += cp[blk*512] * sw[blk];
  ccb[b*1024 + 512 + t] = bf16_rne(acc * invT);
}

// ---------------- output = cc @ Wout^T + bout, bf16 MFMA ----------------
__global__ __launch_bounds__(256) void k_out(
    const unsigned short* __restrict__ ccb, const float* __restrict__ Wout,
    const float* __restrict__ bout, float* __restrict__ out){
  __shared__ short Ccb[32][128][8];      // 64 KB
  __shared__ float s_out[32][65];        // 8.3 KB
  int t = threadIdx.x, wave = t >> 6, lane = t & 63;
  int v0 = blockIdx.x * 64;
  #pragma unroll
  for (int i = 0; i < 16; ++i){
    int c16 = i*256 + t;               // 16B-chunk index over 4096
    int bb = c16 >> 7, ch = c16 & 127;
    int chsw = (ch & ~7) | ((ch & 7) ^ (bb & 7));
    *(short8*)&Ccb[bb][chsw][0] = *(const short8*)(ccb + c16*8);
  }
  __syncthreads();

  int lrow = lane & 15, lk = lane >> 4;
  int vrow = v0 + wave*16 + lrow;
  const float* wptr = Wout + (long)vrow*1024 + lk*8;
  f32x4 acc[2];
  acc[0] = (f32x4){0.f,0.f,0.f,0.f};
  acc[1] = (f32x4){0.f,0.f,0.f,0.f};
  int sw = lrow & 7;
  f32x4 w0 = *(const f32x4*)(wptr);
  f32x4 w1 = *(const f32x4*)(wptr + 4);
  #pragma unroll 4
  for (int ks = 0; ks < 32; ++ks){
    f32x4 nw0, nw1;
    if (ks < 31){
      nw0 = *(const f32x4*)(wptr + (ks+1)*32);
      nw1 = *(const f32x4*)(wptr + (ks+1)*32 + 4);
    }
    short8 bfrag = cvt8(w0, w1);
    int ch = ks*4 + lk;
    int chsw = (ch & ~7) | ((ch & 7) ^ sw);
    short8 a0 = *(const short8*)&Ccb[lrow][chsw][0];
    short8 a1 = *(const short8*)&Ccb[16 + lrow][chsw][0];
    acc[0] = __builtin_amdgcn_mfma_f32_16x16x32_bf16(bfrag, a0, acc[0], 0, 0, 0);
    acc[1] = __builtin_amdgcn_mfma_f32_16x16x32_bf16(bfrag, a1, acc[1], 0, 0, 0);
    w0 = nw0; w1 = nw1;
  }
  #pragma unroll
  for (int mt = 0; mt < 2; ++mt)
    #pragma unroll
    for (int r = 0; r < 4; ++r)
      s_out[mt*16 + lrow][wave*16 + lk*4 + r] = acc[mt][r];
  __syncthreads();
  int vcol = t & 63, bq = t >> 6;
  float bo = bout[v0 + vcol];
  #pragma unroll
  for (int bb = 0; bb < 8; ++bb){
    int brow = bb*4 + bq;
    out[(long)brow*V_ + v0 + vcol] = s_out[brow][vcol] + bo;
  }
}

extern "C" void kernel_launch(void* const* d_in, const int* in_sizes, int n_in,
                              void* d_out, int out_size, void* d_ws, size_t ws_size,
                              hipStream_t stream){
  const float* x    = (const float*)d_in[0];
  const float* h0   = (const float*)d_in[1];
  const float* c0   = (const float*)d_in[2];
  const float* doc  = (const float*)d_in[3];
  const int*   mask = (const int*)d_in[4];
  const float* Wih  = (const float*)d_in[5];
  const float* Whh  = (const float*)d_in[6];
  const float* bih  = (const float*)d_in[7];
  const float* bhh  = (const float*)d_in[8];
  const float* W1   = (const float*)d_in[9];
  const float* b1   = (const float*)d_in[10];
  const float* W2   = (const float*)d_in[11];
  const float* b2   = (const float*)d_in[12];
  const float* u1   = (const float*)d_in[13];
  const float* Wo   = (const float*)d_in[14];
  const float* bo   = (const float*)d_in[15];
  float* out  = (float*)d_out;
  float* outh = out + B_*V_;
  float* outc = outh + B_*H_;

  float* ws    = (float*)d_ws;
  float* gates = ws;                  // 65536 f32
  float* q     = gates + 65536;       // 16384
  float* cc    = q + 16384;           // 32768
  float* ctxp  = cc + 32768;          // 2048*512 = 1048576
  float* bm    = ctxp + 1048576;      // 2048
  float* bs    = bm + 2048;           // 2048
  unsigned short* w2hi = (unsigned short*)(bs + 2048);      // 262144 u16
  unsigned short* ccb  = w2hi + 262144;                     // 32768 u16

  hipLaunchKernelGGL(k_convert_w2, dim3(256), dim3(256), 0, stream, W2, w2hi);
  hipLaunchKernelGGL(k_gates, dim3(8, 32), dim3(256), 0, stream, x, h0, Wih, Whh, bih, bhh, gates);
  hipLaunchKernelGGL(k_lstm, dim3(64), dim3(256), 0, stream, gates, c0, outh, outc, cc, ccb);
  hipLaunchKernelGGL(k_q, dim3(2, 32), dim3(256), 0, stream, cc, W1, b1, q);
  hipLaunchKernelGGL(k_scores_ctx, dim3(2048), dim3(512), 0, stream, doc, w2hi, q, b2, u1, mask, ctxp, bm, bs);
  hipLaunchKernelGGL(k_combine, dim3(32), dim3(512), 0, stream, ctxp, bm, bs, ccb);
  hipLaunchKernelGGL(k_out, dim3(500), dim3(256), 0, stream, ccb, Wo, bo, out);
}